// Round 3
// baseline (681.297 us; speedup 1.0000x reference)
//
#include <hip/hip_runtime.h>

// Layout of samples: [(pixel p)*N + n]*3 + c, p = i*12 + j, i,j in [0,12).
//
// Kernel A (streaming): one thread per (row i, col-cell jc, window-quad q).
//   Reads 4 pixels (j = jc*4..jc*4+3) x 2 inputs x 3 float4 (= 4 windows'
//   triples), accumulates the channel-sum diff pooled over the 4 columns,
//   writes one float4 row-cell partial to ws[(i*3+jc)*N + 4q].
// Kernel B: one thread per window; folds the 4-row pool, computes the
//   4-direction gradient energy, block-reduces, one atomicAdd.

__global__ __launch_bounds__(256) void spa_partial(
    const float* __restrict__ s1, const float* __restrict__ s2,
    float* __restrict__ ws, int N, int Q /* = ceil(N/4) */) {
  const long long t = (long long)blockIdx.x * blockDim.x + threadIdx.x;
  const int s = (int)(t / Q);          // s = i*3 + jc, in [0, 36)
  const int q = (int)(t % Q);
  if (s >= 36) return;
  const int i = s / 3;
  const int jc = s - i * 3;

  float acc0 = 0.f, acc1 = 0.f, acc2 = 0.f, acc3 = 0.f;
  const size_t slab = (size_t)N * 3u;  // floats between pixel slabs

  if (4 * q + 3 < N) {
    // Vector path: 4 whole windows.
    const size_t off = (size_t)q * 12u;
#pragma unroll
    for (int jj = 0; jj < 4; ++jj) {
      const int p = i * 12 + jc * 4 + jj;
      const float4* a4 = (const float4*)(s1 + (size_t)p * slab + off);
      const float4* b4 = (const float4*)(s2 + (size_t)p * slab + off);
      float4 a0 = a4[0], a1 = a4[1], a2 = a4[2];
      float4 b0 = b4[0], b1 = b4[1], b2 = b4[2];
      float4 d0 = make_float4(a0.x - b0.x, a0.y - b0.y, a0.z - b0.z, a0.w - b0.w);
      float4 d1 = make_float4(a1.x - b1.x, a1.y - b1.y, a1.z - b1.z, a1.w - b1.w);
      float4 d2 = make_float4(a2.x - b2.x, a2.y - b2.y, a2.z - b2.z, a2.w - b2.w);
      acc0 += d0.x + d0.y + d0.z;
      acc1 += d0.w + d1.x + d1.y;
      acc2 += d1.z + d1.w + d2.x;
      acc3 += d2.y + d2.z + d2.w;
    }
    float4* w4 = (float4*)(ws + (size_t)s * N + (size_t)q * 4u);
    *w4 = make_float4(acc0, acc1, acc2, acc3);
  } else {
    // Tail: scalar per-window path.
    float acc[4] = {0.f, 0.f, 0.f, 0.f};
#pragma unroll
    for (int jj = 0; jj < 4; ++jj) {
      const int p = i * 12 + jc * 4 + jj;
      const float* a = s1 + (size_t)p * slab;
      const float* b = s2 + (size_t)p * slab;
      for (int w = 0; w < 4; ++w) {
        const int n = 4 * q + w;
        if (n < N) {
          const size_t o = (size_t)n * 3u;
          acc[w] += (a[o] + a[o + 1] + a[o + 2]) - (b[o] + b[o + 1] + b[o + 2]);
        }
      }
    }
    for (int w = 0; w < 4; ++w) {
      const int n = 4 * q + w;
      if (n < N) ws[(size_t)s * N + n] = acc[w];
    }
  }
}

__global__ __launch_bounds__(256) void spa_finish(
    const float* __restrict__ ws, float* __restrict__ out, int N, float scale) {
  const int n = blockIdx.x * blockDim.x + threadIdx.x;
  float e = 0.f;
  if (n < N) {
    // Pool over rows: cell(ip,jc) = sum_{ii} ws[((4ip+ii)*3+jc)*N + n]
    float P[9];
#pragma unroll
    for (int ip = 0; ip < 3; ++ip)
#pragma unroll
      for (int jc = 0; jc < 3; ++jc) {
        float v = 0.f;
#pragma unroll
        for (int ii = 0; ii < 4; ++ii)
          v += ws[(size_t)((4 * ip + ii) * 3 + jc) * N + n];
        P[ip * 3 + jc] = v * (1.0f / 48.0f);
      }
#pragma unroll
    for (int i = 0; i < 3; ++i) {
#pragma unroll
      for (int j = 0; j < 3; ++j) {
        float c = P[i * 3 + j];
        float l = (j > 0) ? P[i * 3 + j - 1] : 0.f;
        float r = (j < 2) ? P[i * 3 + j + 1] : 0.f;
        float u = (i > 0) ? P[(i - 1) * 3 + j] : 0.f;
        float d = (i < 2) ? P[(i + 1) * 3 + j] : 0.f;
        float dl = c - l, dr = c - r, du = c - u, dd = c - d;
        e += dl * dl + dr * dr + du * du + dd * dd;
      }
    }
  }
#pragma unroll
  for (int off = 32; off > 0; off >>= 1) e += __shfl_down(e, off, 64);
  __shared__ float sm[4];
  const int lane = threadIdx.x & 63;
  const int wid = threadIdx.x >> 6;
  if (lane == 0) sm[wid] = e;
  __syncthreads();
  if (threadIdx.x == 0) atomicAdd(out, (sm[0] + sm[1] + sm[2] + sm[3]) * scale);
}

// Fallback (R2 monolithic) if ws is too small — 4 threads/window, 64 win/block.
__global__ __launch_bounds__(256) void spa_mono(
    const float* __restrict__ s1, const float* __restrict__ s2,
    float* __restrict__ out, int N, float scale) {
  const int lane = threadIdx.x & 63;
  const int rg = threadIdx.x >> 6;
  const int win = blockIdx.x * 64 + lane;
  float rowacc[3][3];
#pragma unroll
  for (int a = 0; a < 3; ++a)
#pragma unroll
    for (int b = 0; b < 3; ++b) rowacc[a][b] = 0.f;
  if (win < N) {
    const size_t stride = (size_t)N * 3u;
    const float* p1 = s1 + (size_t)win * 3u;
    const float* p2 = s2 + (size_t)win * 3u;
#pragma unroll
    for (int ii = 0; ii < 3; ++ii) {
      const int i = rg * 3 + ii;
      const float* q1 = p1 + (size_t)(i * 12) * stride;
      const float* q2 = p2 + (size_t)(i * 12) * stride;
#pragma unroll
      for (int j = 0; j < 12; ++j) {
        const float* a = q1 + (size_t)j * stride;
        const float* b = q2 + (size_t)j * stride;
        float d = (a[0] + a[1] + a[2]) - (b[0] + b[1] + b[2]);
        rowacc[ii][j >> 2] += d;
      }
    }
  }
  __shared__ float sRow[12][64][3];
#pragma unroll
  for (int ii = 0; ii < 3; ++ii) {
    const int i = rg * 3 + ii;
#pragma unroll
    for (int c = 0; c < 3; ++c) sRow[i][lane][c] = rowacc[ii][c];
  }
  __syncthreads();
  if (rg == 0) {
    float P[9];
#pragma unroll
    for (int p = 0; p < 3; ++p)
#pragma unroll
      for (int c = 0; c < 3; ++c) {
        float v = sRow[4 * p][lane][c] + sRow[4 * p + 1][lane][c] +
                  sRow[4 * p + 2][lane][c] + sRow[4 * p + 3][lane][c];
        P[p * 3 + c] = v * (1.0f / 48.0f);
      }
    float e = 0.f;
#pragma unroll
    for (int i = 0; i < 3; ++i) {
#pragma unroll
      for (int j = 0; j < 3; ++j) {
        float c = P[i * 3 + j];
        float l = (j > 0) ? P[i * 3 + j - 1] : 0.f;
        float r = (j < 2) ? P[i * 3 + j + 1] : 0.f;
        float u = (i > 0) ? P[(i - 1) * 3 + j] : 0.f;
        float d = (i < 2) ? P[(i + 1) * 3 + j] : 0.f;
        float dl = c - l, dr = c - r, du = c - u, dd = c - d;
        e += dl * dl + dr * dr + du * du + dd * dd;
      }
    }
#pragma unroll
    for (int off = 32; off > 0; off >>= 1) e += __shfl_down(e, off, 64);
    if (lane == 0) atomicAdd(out, e * scale);
  }
}

extern "C" void kernel_launch(void* const* d_in, const int* in_sizes, int n_in,
                              void* d_out, int out_size, void* d_ws, size_t ws_size,
                              hipStream_t stream) {
  const float* s1 = (const float*)d_in[0];
  const float* s2 = (const float*)d_in[1];
  float* out = (float*)d_out;
  const int N = in_sizes[0] / (12 * 12 * 3);
  const float scale = 1.0f / (9.0f * (float)N);
  hipMemsetAsync(d_out, 0, sizeof(float), stream);

  const size_t ws_needed = (size_t)36 * (size_t)N * sizeof(float);
  if (ws_size >= ws_needed) {
    const int Q = (N + 3) / 4;
    const long long threads = 36LL * Q;
    const int blocksA = (int)((threads + 255) / 256);
    spa_partial<<<blocksA, 256, 0, stream>>>(s1, s2, (float*)d_ws, N, Q);
    const int blocksB = (N + 255) / 256;
    spa_finish<<<blocksB, 256, 0, stream>>>((const float*)d_ws, out, N, scale);
  } else {
    const int blocks = (N + 63) / 64;
    spa_mono<<<blocks, 256, 0, stream>>>(s1, s2, out, N, scale);
  }
}